// Round 16
// baseline (335.800 us; speedup 1.0000x reference)
//
#include <hip/hip_runtime.h>
#include <stdint.h>

#define B_ 16
#define S1_ 2048
#define S2_ 2048
#define H_ 512

typedef short short8 __attribute__((ext_vector_type(8)));
typedef float f32x4 __attribute__((ext_vector_type(4)));
typedef long long2v __attribute__((ext_vector_type(2)));

__device__ __forceinline__ unsigned short f2bf(float f) {
  unsigned u = __builtin_bit_cast(unsigned, f);
  u += 0x7fffu + ((u >> 16) & 1u);          // round-to-nearest-even
  return (unsigned short)(u >> 16);
}
__device__ __forceinline__ float bf2f(unsigned short us) {
  return __builtin_bit_cast(float, (unsigned)us << 16);
}

__device__ __forceinline__ void gload_lds16(const void* g, void* l) {
  __builtin_amdgcn_global_load_lds((const __attribute__((address_space(1))) void*)g,
                                   (__attribute__((address_space(3))) void*)l,
                                   16, 0, 0);
}

// ---------------- prep: fp8(normalized, perm) + optional raw bf16 copy ----------------
// fp8 (e4m3) stores x/||x|| DIRECTLY (norm folded into quantization). r12
// lesson: fp8 ONLY for QK^T operands (unit-norm rows bound the ABSOLUTE score
// error); P/V/FF relative error does not average down.
// fp8 stored PERMUTED within each 128-byte K-block: b' = lk*32 + s*8 + j.
template <int WB16>
__global__ __launch_bounds__(256) void k_cast(const float* __restrict__ x,
                                              unsigned short* __restrict__ y,
                                              unsigned char* __restrict__ y8) {
  int row = blockIdx.x * 4 + (threadIdx.x >> 6);
  int l = threadIdx.x & 63;
  const f32x4* xr = (const f32x4*)(x + (size_t)row * H_) + l * 2;
  f32x4 a = xr[0], b = xr[1];
  float s = a[0]*a[0] + a[1]*a[1] + a[2]*a[2] + a[3]*a[3]
          + b[0]*b[0] + b[1]*b[1] + b[2]*b[2] + b[3]*b[3];
#pragma unroll
  for (int m = 1; m < 64; m <<= 1) s += __shfl_xor(s, m);
  float sc = 1.0f / fmaxf(sqrtf(s), 1e-12f);
  if (WB16) {
    short8 o;
#pragma unroll
    for (int i = 0; i < 4; ++i) { o[i] = (short)f2bf(a[i]); o[4 + i] = (short)f2bf(b[i]); }
    *(short8*)(y + (size_t)row * H_ + l * 8) = o;
  }
  int p0 = __builtin_amdgcn_cvt_pk_fp8_f32(a[0] * sc, a[1] * sc, 0, false);
  p0 = __builtin_amdgcn_cvt_pk_fp8_f32(a[2] * sc, a[3] * sc, p0, true);
  int p1 = __builtin_amdgcn_cvt_pk_fp8_f32(b[0] * sc, b[1] * sc, 0, false);
  p1 = __builtin_amdgcn_cvt_pk_fp8_f32(b[2] * sc, b[3] * sc, p1, true);
  int2 pk = {p0, p1};
  int poff = ((l >> 4) * 128) + ((l & 3) * 32) + (((l >> 2) & 3) * 8);
  *(int2*)(y8 + (size_t)row * H_ + poff) = pk;
}

// ---------------- prep: transpose+cast weights W[R][C] -> WT[C][R] bf16 ----------------
__global__ __launch_bounds__(256) void k_tw(const float* __restrict__ Wm,
                                            unsigned short* __restrict__ WT,
                                            int lgR, int C) {
  int i = blockIdx.x * 256 + threadIdx.x;     // over C*R outputs
  int R = 1 << lgR;
  int n = i >> lgR, k = i & (R - 1);
  WT[i] = f2bf(Wm[(size_t)k * C + n]);
}

// ---------------- prep: vt[b][h][s] = transpose(kn[b][s][h]) (bf16 -> bf16) ----------------
__global__ __launch_bounds__(256) void k_tvt(const unsigned short* __restrict__ kn,
                                             unsigned short* __restrict__ vt) {
  __shared__ unsigned short tile[64][72];
  int h0 = blockIdx.x * 64, s0 = blockIdx.y * 64, b = blockIdx.z;
  int t = threadIdx.x;
#pragma unroll
  for (int p = 0; p < 2; ++p) {
    int si = p * 32 + (t >> 3);
    int cj = (t & 7) * 8;
    short8 v = *(const short8*)(kn + ((size_t)(b * S2_ + s0 + si)) * H_ + h0 + cj);
#pragma unroll
    for (int x = 0; x < 8; ++x) tile[si][cj + x] = (unsigned short)v[x];
  }
  __syncthreads();
#pragma unroll
  for (int p = 0; p < 2; ++p) {
    int ho = p * 32 + (t >> 3);
    int sx = (t & 7) * 8;
    short8 o;
#pragma unroll
    for (int x = 0; x < 8; ++x) o[x] = (short)tile[sx + x][ho];
    *(short8*)(vt + ((size_t)(b * H_ + h0 + ho)) * S2_ + s0 + sx) = o;
  }
}

// ---------------- MFMA GEMM: 128x128 tile, 4 waves, COUNTED-VMCNT dbuf LDS ----
// T4 schedule (m218: counted-vs-drain0 = +38-73%): double-buffer 64 KiB LDS;
// per tile t: issue t+1's 8 gload_lds -> s_waitcnt vmcnt(8) (tile t done, t+1
// STAYS IN FLIGHT) -> raw s_barrier -> compute t -> raw s_barrier. The wait
// for tile t has a full compute phase (~1500 cyc) of cover, vs r5's uncovered
// end-of-iteration vmcnt(0) drain (which regressed). Raw barriers mandatory:
// __syncthreads() emits vmcnt(0) and would drain the in-flight tile (m97's
// structural stall). Hazards: buf^1 overwrite only after the barrier ending
// its readers' compute; ds_reads retire before MFMA issue (compiler lgkm
// deps) hence before barrier-2; vmcnt retires in issue order.
// FP8=1: A/B fp8 e4m3 (pre-normalized) in (s,lk)-permuted layout, BK=128.
// Residual 4.19M bank conflicts on fp8 ds_read (ACCEPTED, ~2-3us hidden).
// SWZ: XCD swizzle; ON for pass2/FF, OFF for pass1 (r8 A/B).
// MODE 0: FF1 relu(acc+bias) bf16 | MODE 1: FF2 acc+bias bf16
// MODE 2: P=exp(acc-1)*mask bf16 (no rowsum: LN1 row-scale-inv) | MODE 3: acc bf16
template <int MODE, int SWZ, int FP8>
__global__ __launch_bounds__(256, 2) void k_gemm(
    const void* __restrict__ A, const void* __restrict__ BT,
    const float* __restrict__ bias, const int* __restrict__ mask,
    void* __restrict__ out,
    int M, int N, int K, long sAbytes, long sBbytes, long sOut) {
  __shared__ char lA[2][16384];
  __shared__ char lB[2][16384];

  int bx, by, z;
  if (SWZ) {
    const int gx = gridDim.x, gy = gridDim.y;
    const int nwg = gx * gy * (int)gridDim.z;
    int orig = ((int)blockIdx.z * gy + (int)blockIdx.y) * gx + (int)blockIdx.x;
    int swzid = ((nwg & 7) == 0) ? ((orig & 7) * (nwg >> 3) + (orig >> 3)) : orig;
    z = swzid / (gx * gy);
    int rem = swzid - z * (gx * gy);
    by = rem / gx;
    bx = rem - by * gx;
  } else {
    bx = blockIdx.x; by = blockIdx.y; z = blockIdx.z;
  }

  const int w = threadIdx.x >> 6, l = threadIdx.x & 63;
  const int lr = l & 15, lk = l >> 4;
  const int m0 = by * 128, n0 = bx * 128;
  const int wm = (w >> 1) * 64, wn = (w & 1) * 64;

  // staging: chunk c=j*4+w covers rows 8c..8c+7 (128 B each); lane l covers
  // row 8c+(l>>3), 16 source bytes at col ((l&7)*16) ^ XOR-swizzle; dest linear.
  const size_t rowbytes = (size_t)K * (FP8 ? 1 : 2);
  const int srow = l >> 3;
  const int lswz = ((l & 7) * 16) ^ ((srow & 7) << 4);
  const char* pA = (const char*)A + (size_t)z * sAbytes + (size_t)(m0 + w * 8 + srow) * rowbytes + lswz;
  const char* pB = (const char*)BT + (size_t)z * sBbytes + (size_t)(n0 + w * 8 + srow) * rowbytes + lswz;
  const size_t rstep = rowbytes * 32;   // 32 rows per j-step

  f32x4 acc[4][4];
#pragma unroll
  for (int i = 0; i < 4; ++i)
#pragma unroll
    for (int j = 0; j < 4; ++j) acc[i][j] = (f32x4){0.f, 0.f, 0.f, 0.f};

  const int NT = K >> (FP8 ? 7 : 6);

  // prologue: stage tile 0 -> buf 0 (8 loads, left in flight)
#pragma unroll
  for (int j = 0; j < 4; ++j) {
    gload_lds16(pA + j * rstep, lA[0] + (j * 4 + w) * 1024);
    gload_lds16(pB + j * rstep, lB[0] + (j * 4 + w) * 1024);
  }

#pragma unroll 1
  for (int t = 0; t < NT; ++t) {
    const int cur = t & 1;
    // issue tile t+1's staging (8 loads) -- stays in flight across compute(t)
    if (t + 1 < NT) {
      const size_t kb = (size_t)(t + 1) * 128;
#pragma unroll
      for (int j = 0; j < 4; ++j) {
        gload_lds16(pA + j * rstep + kb, lA[cur ^ 1] + (j * 4 + w) * 1024);
        gload_lds16(pB + j * rstep + kb, lB[cur ^ 1] + (j * 4 + w) * 1024);
      }
      asm volatile("s_waitcnt vmcnt(8)" ::: "memory");   // tile t done; t+1 in flight
    } else {
      asm volatile("s_waitcnt vmcnt(0)" ::: "memory");   // last tile: drain
    }
    __builtin_amdgcn_s_barrier();
    asm volatile("" ::: "memory");   // no ds_read hoisting above the barrier

    if (FP8) {
      const char* As = lA[cur];
      const char* Bs = lB[cur];
#pragma unroll
      for (int s2 = 0; s2 < 2; ++s2) {
        long2v af[4], bf[4];
#pragma unroll
        for (int mi = 0; mi < 4; ++mi) {
          int row = wm + mi * 16 + lr;
          short8 tmp = *(const short8*)(As + row * 128 + ((lk * 32 + s2 * 16) ^ ((row & 7) << 4)));
          af[mi] = __builtin_bit_cast(long2v, tmp);
        }
#pragma unroll
        for (int ni = 0; ni < 4; ++ni) {
          int row = wn + ni * 16 + lr;
          short8 tmp = *(const short8*)(Bs + row * 128 + ((lk * 32 + s2 * 16) ^ ((row & 7) << 4)));
          bf[ni] = __builtin_bit_cast(long2v, tmp);
        }
#pragma unroll
        for (int mi = 0; mi < 4; ++mi)
#pragma unroll
          for (int ni = 0; ni < 4; ++ni) {
            acc[mi][ni] = __builtin_amdgcn_mfma_f32_16x16x32_fp8_fp8(af[mi].x, bf[ni].x, acc[mi][ni], 0, 0, 0);
            acc[mi][ni] = __builtin_amdgcn_mfma_f32_16x16x32_fp8_fp8(af[mi].y, bf[ni].y, acc[mi][ni], 0, 0, 0);
          }
      }
    } else {
      const unsigned short* As = (const unsigned short*)lA[cur];
      const unsigned short* Bs = (const unsigned short*)lB[cur];
#pragma unroll
      for (int s = 0; s < 2; ++s) {
        short8 af[4], bf[4];
#pragma unroll
        for (int mi = 0; mi < 4; ++mi) {
          int row = wm + mi * 16 + lr;
          af[mi] = *(const short8*)(As + row * 64 + ((s * 32 + lk * 8) ^ ((row & 7) << 3)));
        }
#pragma unroll
        for (int ni = 0; ni < 4; ++ni) {
          int row = wn + ni * 16 + lr;
          bf[ni] = *(const short8*)(Bs + row * 64 + ((s * 32 + lk * 8) ^ ((row & 7) << 3)));
        }
#pragma unroll
        for (int mi = 0; mi < 4; ++mi)
#pragma unroll
          for (int ni = 0; ni < 4; ++ni)
            acc[mi][ni] = __builtin_amdgcn_mfma_f32_16x16x32_bf16(af[mi], bf[ni], acc[mi][ni], 0, 0, 0);
      }
    }

    asm volatile("" ::: "memory");   // ds_reads retired (pre-MFMA lgkm deps)
    __builtin_amdgcn_s_barrier();    // readers done -> buf may be overwritten
  }

  if (MODE == 2) {
    float mv[4];
#pragma unroll
    for (int ni = 0; ni < 4; ++ni) {
      int gn = n0 + wn + ni * 16 + lr;
      mv[ni] = (mask[(size_t)z * N + gn] != 0) ? 1.0f : 0.0f;
    }
#pragma unroll
    for (int mi = 0; mi < 4; ++mi)
#pragma unroll
      for (int ni = 0; ni < 4; ++ni) {
        int gn = n0 + wn + ni * 16 + lr;
#pragma unroll
        for (int r = 0; r < 4; ++r) {
          int gm = m0 + wm + mi * 16 + lk * 4 + r;
          float p = __expf(acc[mi][ni][r] - 1.0f) * mv[ni];
          ((unsigned short*)out)[(size_t)z * sOut + (size_t)gm * N + gn] = f2bf(p);
        }
      }
  } else if (MODE == 3) {
#pragma unroll
    for (int mi = 0; mi < 4; ++mi)
#pragma unroll
      for (int r = 0; r < 4; ++r) {
        int gm = m0 + wm + mi * 16 + lk * 4 + r;
#pragma unroll
        for (int ni = 0; ni < 4; ++ni) {
          int gn = n0 + wn + ni * 16 + lr;
          ((unsigned short*)out)[(size_t)z * sOut + (size_t)gm * N + gn] = f2bf(acc[mi][ni][r]);
        }
      }
  } else {
#pragma unroll
    for (int mi = 0; mi < 4; ++mi)
#pragma unroll
      for (int ni = 0; ni < 4; ++ni) {
        int gn = n0 + wn + ni * 16 + lr;
        float bs = bias[gn];
#pragma unroll
        for (int r = 0; r < 4; ++r) {
          int gm = m0 + wm + mi * 16 + lk * 4 + r;
          float v = acc[mi][ni][r] + bs;
          if (MODE == 0) v = fmaxf(v, 0.f);
          ((unsigned short*)out)[(size_t)gm * N + gn] = f2bf(v);
        }
      }
  }
}

// ---------------- LN1: nattn = LN(O)*g+b (bf16); O unnormalized (LN scale-inv) ----
__global__ __launch_bounds__(256) void k_ln1(const unsigned short* __restrict__ O,
                                             const float* __restrict__ g,
                                             const float* __restrict__ bvec,
                                             unsigned short* __restrict__ nattn) {
  int row = blockIdx.x * 4 + (threadIdx.x >> 6);
  int l = threadIdx.x & 63;
  size_t base = (size_t)row * H_ + l * 8;
  short8 ov = *(const short8*)(O + base);
  float x[8];
#pragma unroll
  for (int i = 0; i < 8; ++i) x[i] = bf2f((unsigned short)ov[i]);
  float s = 0.f, q = 0.f;
#pragma unroll
  for (int i = 0; i < 8; ++i) { s += x[i]; q += x[i] * x[i]; }
#pragma unroll
  for (int m = 1; m < 64; m <<= 1) { s += __shfl_xor(s, m); q += __shfl_xor(q, m); }
  float mean = s * (1.f / 512.f);
  float var = q * (1.f / 512.f) - mean * mean;
  float rstd = rsqrtf(var + 1e-6f);
  f32x4 g0 = *(const f32x4*)(g + l * 8), g1v = *(const f32x4*)(g + l * 8 + 4);
  f32x4 b0 = *(const f32x4*)(bvec + l * 8), b1v = *(const f32x4*)(bvec + l * 8 + 4);
  short8 no;
#pragma unroll
  for (int i = 0; i < 4; ++i) {
    no[i]     = (short)f2bf((x[i] - mean) * rstd * g0[i] + b0[i]);
    no[4 + i] = (short)f2bf((x[4 + i] - mean) * rstd * g1v[i] + b1v[i]);
  }
  *(short8*)(nattn + base) = no;
}

// ---------------- LN2(ff bf16) + nattn + text1 -> out ----------------
__global__ __launch_bounds__(256) void k_ln2(const unsigned short* __restrict__ ff,
                                             const unsigned short* __restrict__ nattn,
                                             const float* __restrict__ text1,
                                             const float* __restrict__ g2,
                                             const float* __restrict__ bb2,
                                             float* __restrict__ out) {
  int row = blockIdx.x * 4 + (threadIdx.x >> 6);
  int l = threadIdx.x & 63;
  size_t base = (size_t)row * H_ + l * 8;
  short8 fv = *(const short8*)(ff + base);
  float x[8];
#pragma unroll
  for (int i = 0; i < 8; ++i) x[i] = bf2f((unsigned short)fv[i]);
  float s = 0.f, q = 0.f;
#pragma unroll
  for (int i = 0; i < 8; ++i) { s += x[i]; q += x[i] * x[i]; }
#pragma unroll
  for (int m = 1; m < 64; m <<= 1) { s += __shfl_xor(s, m); q += __shfl_xor(q, m); }
  float mean = s * (1.f / 512.f);
  float var = q * (1.f / 512.f) - mean * mean;
  float rstd = rsqrtf(var + 1e-6f);
  f32x4 g0 = *(const f32x4*)(g2 + l * 8), g1v = *(const f32x4*)(g2 + l * 8 + 4);
  f32x4 b0 = *(const f32x4*)(bb2 + l * 8), b1v = *(const f32x4*)(bb2 + l * 8 + 4);
  short8 nv = *(const short8*)(nattn + base);
  f32x4 t0 = *(const f32x4*)(text1 + base), t1 = *(const f32x4*)(text1 + base + 4);
  f32x4 o0, o1;
#pragma unroll
  for (int i = 0; i < 4; ++i) {
    o0[i] = (x[i] - mean) * rstd * g0[i] + b0[i] + bf2f((unsigned short)nv[i]) + t0[i];
    o1[i] = (x[4 + i] - mean) * rstd * g1v[i] + b1v[i] + bf2f((unsigned short)nv[4 + i]) + t1[i];
  }
  *(f32x4*)(out + base) = o0;
  *(f32x4*)(out + base + 4) = o1;
}

extern "C" void kernel_launch(void* const* d_in, const int* in_sizes, int n_in,
                              void* d_out, int out_size, void* d_ws, size_t ws_size,
                              hipStream_t stream) {
  const float* text1 = (const float*)d_in[0];
  const float* text2 = (const float*)d_in[1];
  // d_in[2] = text1_mask (unused by reference output)
  const int* mask2 = (const int*)d_in[3];
  const float* W1 = (const float*)d_in[4];
  const float* b1 = (const float*)d_in[5];
  const float* W2 = (const float*)d_in[6];
  const float* b2 = (const float*)d_in[7];
  const float* g1 = (const float*)d_in[8];
  const float* bb1 = (const float*)d_in[9];
  const float* g2 = (const float*)d_in[10];
  const float* bb2 = (const float*)d_in[11];

  const size_t MiB = 1024ull * 1024ull;
  char* ws = (char*)d_ws;
  // ---- layout (max offset 196 MiB) ----
  unsigned short* W1T   = (unsigned short*)(ws + 0 * MiB);          // 1 MiB
  unsigned short* W2T   = (unsigned short*)(ws + 1 * MiB);          // 1 MiB
  unsigned char*  qn8   = (unsigned char*)(ws + 4 * MiB);     // 16 MiB [4,20)
  unsigned char*  kn8   = (unsigned char*)(ws + 20 * MiB);    // 16 MiB [20,36)
  unsigned short* kn    = (unsigned short*)(ws + 36 * MiB);   // 32 MiB [36,68): dead after k_tvt
  unsigned short* vt    = (unsigned short*)(ws + 164 * MiB);  // 32 MiB [164,196): dead after pass2
  unsigned short* P     = (unsigned short*)(ws + 36 * MiB);   // 128 MiB [36,164) over kn (dead);
                                                              //   all 16 batches, dead after pass2
  unsigned short* O     = (unsigned short*)(ws + 4 * MiB);    // 32 MiB [4,36) over qn8+kn8 (dead
                                                              //   after pass1; pass2 runs later)
  // aliases (stream-order lifetimes; each span checked against later readers):
  unsigned short* nattn = (unsigned short*)(ws + 100 * MiB);  // [100,132) over P-mid (dead after
                                                              //   pass2); live LN1 -> LN2; nothing
                                                              //   writes [100,132) in between (FF1
                                                              //   -> [132,196), FF2 -> [36,68)).
  unsigned short* hbuf  = (unsigned short*)(ws + 132 * MiB);  // [132,196) over P-upper + vt (both
                                                              //   dead after pass2)
  unsigned short* ffb   = (unsigned short*)(ws + 36 * MiB);   // [36,68) over P-lower (dead); NOT
                                                              //   overlapping nattn (round-4 bug)
  float* outp = (float*)d_out;

  k_cast<0><<<dim3(B_ * S1_ / 4), 256, 0, stream>>>(text1, nullptr, qn8);
  k_cast<1><<<dim3(B_ * S2_ / 4), 256, 0, stream>>>(text2, kn, kn8);
  k_tw<<<dim3(512 * 1024 / 256), 256, 0, stream>>>(W1, W1T, 9, 1024);
  k_tw<<<dim3(512 * 1024 / 256), 256, 0, stream>>>(W2, W2T, 10, 512);
  k_tvt<<<dim3(H_ / 64, S2_ / 64, B_), 256, 0, stream>>>(kn, vt);

  // pass1 (fp8 pre-normalized, BK=128), all 16 batches: P = exp(q8@k8^T - 1)*mask [SWZ=0]
  k_gemm<2, 0, 1><<<dim3(S2_ / 128, S1_ / 128, B_), 256, 0, stream>>>(
      qn8, kn8, nullptr, mask2,
      P, S1_, S2_, H_, (long)S1_ * H_, (long)S2_ * H_, (long)S1_ * S2_);
  // pass2 (bf16), all 16 batches: O = P @ V (unnormalized; LN1 washes row scale)
  k_gemm<3, 1, 0><<<dim3(H_ / 128, S1_ / 128, B_), 256, 0, stream>>>(
      P, vt, nullptr, nullptr,
      O, S1_, H_, S2_, (long)S1_ * S2_ * 2, (long)H_ * S2_ * 2, (long)S1_ * H_);

  k_ln1<<<dim3(B_ * S1_ / 4), 256, 0, stream>>>(O, g1, bb1, nattn);
  k_gemm<0, 1, 0><<<dim3(1024 / 128, 32768 / 128, 1), 256, 0, stream>>>(
      nattn, W1T, b1, nullptr, hbuf, 32768, 1024, 512, 0, 0, 0);
  k_gemm<1, 1, 0><<<dim3(512 / 128, 32768 / 128, 1), 256, 0, stream>>>(
      hbuf, W2T, b2, nullptr, ffb, 32768, 512, 1024, 0, 0, 0);
  k_ln2<<<dim3(32768 / 4), 256, 0, stream>>>(ffb, nattn, text1, g2, bb2, outp);
}

// Round 17
// 291.076 us; speedup vs baseline: 1.1536x; 1.1536x over previous
//
#include <hip/hip_runtime.h>
#include <stdint.h>

#define B_ 16
#define S1_ 2048
#define S2_ 2048
#define H_ 512

typedef short short8 __attribute__((ext_vector_type(8)));
typedef float f32x4 __attribute__((ext_vector_type(4)));
typedef long long2v __attribute__((ext_vector_type(2)));

__device__ __forceinline__ unsigned short f2bf(float f) {
  unsigned u = __builtin_bit_cast(unsigned, f);
  u += 0x7fffu + ((u >> 16) & 1u);          // round-to-nearest-even
  return (unsigned short)(u >> 16);
}
__device__ __forceinline__ float bf2f(unsigned short us) {
  return __builtin_bit_cast(float, (unsigned)us << 16);
}

__device__ __forceinline__ void gload_lds16(const void* g, void* l) {
  __builtin_amdgcn_global_load_lds((const __attribute__((address_space(1))) void*)g,
                                   (__attribute__((address_space(3))) void*)l,
                                   16, 0, 0);
}

// ---------------- prep: fp8(normalized, perm) + optional raw bf16 copy ----------------
// fp8 (e4m3) stores x/||x|| DIRECTLY (norm folded into quantization). r12
// lesson: fp8 ONLY for QK^T operands (unit-norm rows bound the ABSOLUTE score
// error, eps/sqrt(512)); P/V/FF relative error does NOT average down.
// fp8 stored PERMUTED within each 128-byte K-block: b' = lk*32 + s*8 + j.
template <int WB16>
__global__ __launch_bounds__(256) void k_cast(const float* __restrict__ x,
                                              unsigned short* __restrict__ y,
                                              unsigned char* __restrict__ y8) {
  int row = blockIdx.x * 4 + (threadIdx.x >> 6);
  int l = threadIdx.x & 63;
  const f32x4* xr = (const f32x4*)(x + (size_t)row * H_) + l * 2;
  f32x4 a = xr[0], b = xr[1];
  float s = a[0]*a[0] + a[1]*a[1] + a[2]*a[2] + a[3]*a[3]
          + b[0]*b[0] + b[1]*b[1] + b[2]*b[2] + b[3]*b[3];
#pragma unroll
  for (int m = 1; m < 64; m <<= 1) s += __shfl_xor(s, m);
  float sc = 1.0f / fmaxf(sqrtf(s), 1e-12f);   // all lanes hold the full sum
  if (WB16) {
    short8 o;
#pragma unroll
    for (int i = 0; i < 4; ++i) { o[i] = (short)f2bf(a[i]); o[4 + i] = (short)f2bf(b[i]); }
    *(short8*)(y + (size_t)row * H_ + l * 8) = o;
  }
  int p0 = __builtin_amdgcn_cvt_pk_fp8_f32(a[0] * sc, a[1] * sc, 0, false);
  p0 = __builtin_amdgcn_cvt_pk_fp8_f32(a[2] * sc, a[3] * sc, p0, true);
  int p1 = __builtin_amdgcn_cvt_pk_fp8_f32(b[0] * sc, b[1] * sc, 0, false);
  p1 = __builtin_amdgcn_cvt_pk_fp8_f32(b[2] * sc, b[3] * sc, p1, true);
  int2 pk = {p0, p1};
  // lane l covers orig bytes [l*8, l*8+8): t=l>>4 (128B block), s=(l>>2)&3, lk=l&3
  int poff = ((l >> 4) * 128) + ((l & 3) * 32) + (((l >> 2) & 3) * 8);
  *(int2*)(y8 + (size_t)row * H_ + poff) = pk;
}

// ---------------- prep: transpose+cast weights W[R][C] -> WT[C][R] bf16 ----------------
__global__ __launch_bounds__(256) void k_tw(const float* __restrict__ Wm,
                                            unsigned short* __restrict__ WT,
                                            int lgR, int C) {
  int i = blockIdx.x * 256 + threadIdx.x;     // over C*R outputs
  int R = 1 << lgR;
  int n = i >> lgR, k = i & (R - 1);
  WT[i] = f2bf(Wm[(size_t)k * C + n]);
}

// ---------------- prep: vt[b][h][s] = transpose(kn[b][s][h]) (bf16 -> bf16) ----------------
__global__ __launch_bounds__(256) void k_tvt(const unsigned short* __restrict__ kn,
                                             unsigned short* __restrict__ vt) {
  __shared__ unsigned short tile[64][72];
  int h0 = blockIdx.x * 64, s0 = blockIdx.y * 64, b = blockIdx.z;
  int t = threadIdx.x;
#pragma unroll
  for (int p = 0; p < 2; ++p) {
    int si = p * 32 + (t >> 3);
    int cj = (t & 7) * 8;
    short8 v = *(const short8*)(kn + ((size_t)(b * S2_ + s0 + si)) * H_ + h0 + cj);
#pragma unroll
    for (int x = 0; x < 8; ++x) tile[si][cj + x] = (unsigned short)v[x];
  }
  __syncthreads();
#pragma unroll
  for (int p = 0; p < 2; ++p) {
    int ho = p * 32 + (t >> 3);
    int sx = (t & 7) * 8;
    short8 o;
#pragma unroll
    for (int x = 0; x < 8; ++x) o[x] = (short)tile[sx + x][ho];
    *(short8*)(vt + ((size_t)(b * H_ + h0 + ho)) * S2_ + s0 + sx) = o;
  }
}

// ---------------- MFMA GEMM: 128-row tile, 4 waves, single-buf 32 KiB LDS ----
// FINAL structure, measured optimum for this workload: stage -> vmcnt(0) ->
// barrier -> compute -> barrier; 3-4 blocks/CU residency + cross-block TLP
// hides staging latency. Three deeper-pipeline probes all regressed:
//   r3  256^2-tile 8-wave issue-early      -> 57 -> 76 us (1 blk/CU)
//   r5  2-phase dbuf, drain after compute  -> 57 -> 78 us (2 blk/CU)
//   r16 counted-vmcnt dbuf, raw barriers   -> 64 -> 80 us (2 blk/CU)
// (T4-class schedules only pay inside the full 8-phase 256^2 co-design.)
// FP8=1: A/B fp8 e4m3 (pre-normalized) in (s,lk)-permuted layout, BK=128.
// Residual 4.19M bank conflicts on fp8 ds_read (compiler splits the 16B read
// into 2x b64; 3 fix attempts failed; ~2-3us hidden cost -- ACCEPTED).
// SWZ: XCD swizzle; ON for pass2/FF (panel L2 locality), OFF for pass1 (r8 A/B:
// swizzle concentrated pass1's working set on one XCD L2, +10us).
// MODE 0: FF1 relu(acc+bias) bf16 | MODE 1: FF2 acc+bias bf16
// MODE 2: P=exp(acc-1)*mask bf16 (no rowsum: LN1 row-scale-inv) | MODE 3: acc bf16
template <int MODE, int SWZ, int FP8>
__global__ __launch_bounds__(256, 2) void k_gemm(
    const void* __restrict__ A, const void* __restrict__ BT,
    const float* __restrict__ bias, const int* __restrict__ mask,
    void* __restrict__ out,
    int M, int N, int K, long sAbytes, long sBbytes, long sOut) {
  __shared__ char lA[16384];
  __shared__ char lB[16384];

  int bx, by, z;
  if (SWZ) {
    const int gx = gridDim.x, gy = gridDim.y;
    const int nwg = gx * gy * (int)gridDim.z;
    int orig = ((int)blockIdx.z * gy + (int)blockIdx.y) * gx + (int)blockIdx.x;
    int swzid = ((nwg & 7) == 0) ? ((orig & 7) * (nwg >> 3) + (orig >> 3)) : orig;
    z = swzid / (gx * gy);
    int rem = swzid - z * (gx * gy);
    by = rem / gx;
    bx = rem - by * gx;
  } else {
    bx = blockIdx.x; by = blockIdx.y; z = blockIdx.z;
  }

  const int w = threadIdx.x >> 6, l = threadIdx.x & 63;
  const int lr = l & 15, lk = l >> 4;
  const int m0 = by * 128, n0 = bx * 128;
  const int wm = (w >> 1) * 64, wn = (w & 1) * 64;

  // staging: chunk c=j*4+w covers rows 8c..8c+7 (128 B each); lane l covers
  // row 8c+(l>>3), 16 source bytes at col ((l&7)*16) ^ XOR-swizzle; dest linear.
  const size_t rowbytes = (size_t)K * (FP8 ? 1 : 2);
  const int srow = l >> 3;
  const int lswz = ((l & 7) * 16) ^ ((srow & 7) << 4);
  const char* pA = (const char*)A + (size_t)z * sAbytes + (size_t)(m0 + w * 8 + srow) * rowbytes + lswz;
  const char* pB = (const char*)BT + (size_t)z * sBbytes + (size_t)(n0 + w * 8 + srow) * rowbytes + lswz;
  const size_t rstep = rowbytes * 32;   // 32 rows per j-step

  f32x4 acc[4][4];
#pragma unroll
  for (int i = 0; i < 4; ++i)
#pragma unroll
    for (int j = 0; j < 4; ++j) acc[i][j] = (f32x4){0.f, 0.f, 0.f, 0.f};

  const int NT = K >> (FP8 ? 7 : 6);

#pragma unroll 1
  for (int t = 0; t < NT; ++t) {
    const size_t kb = (size_t)t * 128;   // 128 B per tile step in both dtypes
#pragma unroll
    for (int j = 0; j < 4; ++j) {
      gload_lds16(pA + j * rstep + kb, lA + (j * 4 + w) * 1024);
      gload_lds16(pB + j * rstep + kb, lB + (j * 4 + w) * 1024);
    }
    asm volatile("s_waitcnt vmcnt(0)" ::: "memory");
    __syncthreads();
    if (FP8) {
      // permuted layout: one 16B slot at (lk*32 + s2*16) ^ swz holds the
      // s=2*s2 and s=2*s2+1 fragments.
#pragma unroll
      for (int s2 = 0; s2 < 2; ++s2) {
        long2v af[4], bf[4];
#pragma unroll
        for (int mi = 0; mi < 4; ++mi) {
          int row = wm + mi * 16 + lr;
          short8 tmp = *(const short8*)(lA + row * 128 + ((lk * 32 + s2 * 16) ^ ((row & 7) << 4)));
          af[mi] = __builtin_bit_cast(long2v, tmp);
        }
#pragma unroll
        for (int ni = 0; ni < 4; ++ni) {
          int row = wn + ni * 16 + lr;
          short8 tmp = *(const short8*)(lB + row * 128 + ((lk * 32 + s2 * 16) ^ ((row & 7) << 4)));
          bf[ni] = __builtin_bit_cast(long2v, tmp);
        }
#pragma unroll
        for (int mi = 0; mi < 4; ++mi)
#pragma unroll
          for (int ni = 0; ni < 4; ++ni) {
            acc[mi][ni] = __builtin_amdgcn_mfma_f32_16x16x32_fp8_fp8(af[mi].x, bf[ni].x, acc[mi][ni], 0, 0, 0);
            acc[mi][ni] = __builtin_amdgcn_mfma_f32_16x16x32_fp8_fp8(af[mi].y, bf[ni].y, acc[mi][ni], 0, 0, 0);
          }
      }
    } else {
      const unsigned short* As = (const unsigned short*)lA;
      const unsigned short* Bs = (const unsigned short*)lB;
#pragma unroll
      for (int s = 0; s < 2; ++s) {
        short8 af[4], bf[4];
#pragma unroll
        for (int mi = 0; mi < 4; ++mi) {
          int row = wm + mi * 16 + lr;
          af[mi] = *(const short8*)(As + row * 64 + ((s * 32 + lk * 8) ^ ((row & 7) << 3)));
        }
#pragma unroll
        for (int ni = 0; ni < 4; ++ni) {
          int row = wn + ni * 16 + lr;
          bf[ni] = *(const short8*)(Bs + row * 64 + ((s * 32 + lk * 8) ^ ((row & 7) << 3)));
        }
#pragma unroll
        for (int mi = 0; mi < 4; ++mi)
#pragma unroll
          for (int ni = 0; ni < 4; ++ni)
            acc[mi][ni] = __builtin_amdgcn_mfma_f32_16x16x32_bf16(af[mi], bf[ni], acc[mi][ni], 0, 0, 0);
      }
    }
    __syncthreads();
  }

  if (MODE == 2) {
    float mv[4];
#pragma unroll
    for (int ni = 0; ni < 4; ++ni) {
      int gn = n0 + wn + ni * 16 + lr;
      mv[ni] = (mask[(size_t)z * N + gn] != 0) ? 1.0f : 0.0f;
    }
#pragma unroll
    for (int mi = 0; mi < 4; ++mi)
#pragma unroll
      for (int ni = 0; ni < 4; ++ni) {
        int gn = n0 + wn + ni * 16 + lr;
#pragma unroll
        for (int r = 0; r < 4; ++r) {
          int gm = m0 + wm + mi * 16 + lk * 4 + r;
          float p = __expf(acc[mi][ni][r] - 1.0f) * mv[ni];
          ((unsigned short*)out)[(size_t)z * sOut + (size_t)gm * N + gn] = f2bf(p);
        }
      }
  } else if (MODE == 3) {
#pragma unroll
    for (int mi = 0; mi < 4; ++mi)
#pragma unroll
      for (int r = 0; r < 4; ++r) {
        int gm = m0 + wm + mi * 16 + lk * 4 + r;
#pragma unroll
        for (int ni = 0; ni < 4; ++ni) {
          int gn = n0 + wn + ni * 16 + lr;
          ((unsigned short*)out)[(size_t)z * sOut + (size_t)gm * N + gn] = f2bf(acc[mi][ni][r]);
        }
      }
  } else {
#pragma unroll
    for (int mi = 0; mi < 4; ++mi)
#pragma unroll
      for (int ni = 0; ni < 4; ++ni) {
        int gn = n0 + wn + ni * 16 + lr;
        float bs = bias[gn];
#pragma unroll
        for (int r = 0; r < 4; ++r) {
          int gm = m0 + wm + mi * 16 + lk * 4 + r;
          float v = acc[mi][ni][r] + bs;
          if (MODE == 0) v = fmaxf(v, 0.f);
          ((unsigned short*)out)[(size_t)gm * N + gn] = f2bf(v);
        }
      }
  }
}

// ---------------- LN1: nattn = LN(O)*g+b (bf16); O unnormalized (LN scale-inv) ----
__global__ __launch_bounds__(256) void k_ln1(const unsigned short* __restrict__ O,
                                             const float* __restrict__ g,
                                             const float* __restrict__ bvec,
                                             unsigned short* __restrict__ nattn) {
  int row = blockIdx.x * 4 + (threadIdx.x >> 6);
  int l = threadIdx.x & 63;
  size_t base = (size_t)row * H_ + l * 8;
  short8 ov = *(const short8*)(O + base);
  float x[8];
#pragma unroll
  for (int i = 0; i < 8; ++i) x[i] = bf2f((unsigned short)ov[i]);
  float s = 0.f, q = 0.f;
#pragma unroll
  for (int i = 0; i < 8; ++i) { s += x[i]; q += x[i] * x[i]; }
#pragma unroll
  for (int m = 1; m < 64; m <<= 1) { s += __shfl_xor(s, m); q += __shfl_xor(q, m); }
  float mean = s * (1.f / 512.f);
  float var = q * (1.f / 512.f) - mean * mean;
  float rstd = rsqrtf(var + 1e-6f);
  f32x4 g0 = *(const f32x4*)(g + l * 8), g1v = *(const f32x4*)(g + l * 8 + 4);
  f32x4 b0 = *(const f32x4*)(bvec + l * 8), b1v = *(const f32x4*)(bvec + l * 8 + 4);
  short8 no;
#pragma unroll
  for (int i = 0; i < 4; ++i) {
    no[i]     = (short)f2bf((x[i] - mean) * rstd * g0[i] + b0[i]);
    no[4 + i] = (short)f2bf((x[4 + i] - mean) * rstd * g1v[i] + b1v[i]);
  }
  *(short8*)(nattn + base) = no;
}

// ---------------- LN2(ff bf16) + nattn + text1 -> out ----------------
__global__ __launch_bounds__(256) void k_ln2(const unsigned short* __restrict__ ff,
                                             const unsigned short* __restrict__ nattn,
                                             const float* __restrict__ text1,
                                             const float* __restrict__ g2,
                                             const float* __restrict__ bb2,
                                             float* __restrict__ out) {
  int row = blockIdx.x * 4 + (threadIdx.x >> 6);
  int l = threadIdx.x & 63;
  size_t base = (size_t)row * H_ + l * 8;
  short8 fv = *(const short8*)(ff + base);
  float x[8];
#pragma unroll
  for (int i = 0; i < 8; ++i) x[i] = bf2f((unsigned short)fv[i]);
  float s = 0.f, q = 0.f;
#pragma unroll
  for (int i = 0; i < 8; ++i) { s += x[i]; q += x[i] * x[i]; }
#pragma unroll
  for (int m = 1; m < 64; m <<= 1) { s += __shfl_xor(s, m); q += __shfl_xor(q, m); }
  float mean = s * (1.f / 512.f);
  float var = q * (1.f / 512.f) - mean * mean;
  float rstd = rsqrtf(var + 1e-6f);
  f32x4 g0 = *(const f32x4*)(g2 + l * 8), g1v = *(const f32x4*)(g2 + l * 8 + 4);
  f32x4 b0 = *(const f32x4*)(bb2 + l * 8), b1v = *(const f32x4*)(bb2 + l * 8 + 4);
  short8 nv = *(const short8*)(nattn + base);
  f32x4 t0 = *(const f32x4*)(text1 + base), t1 = *(const f32x4*)(text1 + base + 4);
  f32x4 o0, o1;
#pragma unroll
  for (int i = 0; i < 4; ++i) {
    o0[i] = (x[i] - mean) * rstd * g0[i] + b0[i] + bf2f((unsigned short)nv[i]) + t0[i];
    o1[i] = (x[4 + i] - mean) * rstd * g1v[i] + b1v[i] + bf2f((unsigned short)nv[4 + i]) + t1[i];
  }
  *(f32x4*)(out + base) = o0;
  *(f32x4*)(out + base + 4) = o1;
}

extern "C" void kernel_launch(void* const* d_in, const int* in_sizes, int n_in,
                              void* d_out, int out_size, void* d_ws, size_t ws_size,
                              hipStream_t stream) {
  const float* text1 = (const float*)d_in[0];
  const float* text2 = (const float*)d_in[1];
  // d_in[2] = text1_mask (unused by reference output)
  const int* mask2 = (const int*)d_in[3];
  const float* W1 = (const float*)d_in[4];
  const float* b1 = (const float*)d_in[5];
  const float* W2 = (const float*)d_in[6];
  const float* b2 = (const float*)d_in[7];
  const float* g1 = (const float*)d_in[8];
  const float* bb1 = (const float*)d_in[9];
  const float* g2 = (const float*)d_in[10];
  const float* bb2 = (const float*)d_in[11];

  const size_t MiB = 1024ull * 1024ull;
  char* ws = (char*)d_ws;
  // ---- layout (max offset 196 MiB) ----
  unsigned short* W1T   = (unsigned short*)(ws + 0 * MiB);          // 1 MiB
  unsigned short* W2T   = (unsigned short*)(ws + 1 * MiB);          // 1 MiB
  unsigned char*  qn8   = (unsigned char*)(ws + 4 * MiB);     // 16 MiB [4,20)
  unsigned char*  kn8   = (unsigned char*)(ws + 20 * MiB);    // 16 MiB [20,36)
  unsigned short* kn    = (unsigned short*)(ws + 36 * MiB);   // 32 MiB [36,68): dead after k_tvt
  unsigned short* vt    = (unsigned short*)(ws + 164 * MiB);  // 32 MiB [164,196): dead after pass2
  unsigned short* P     = (unsigned short*)(ws + 36 * MiB);   // 128 MiB [36,164) over kn (dead);
                                                              //   all 16 batches, dead after pass2
  unsigned short* O     = (unsigned short*)(ws + 4 * MiB);    // 32 MiB [4,36) over qn8+kn8 (dead
                                                              //   after pass1; pass2 runs later)
  // aliases (stream-order lifetimes; each span checked against later readers):
  unsigned short* nattn = (unsigned short*)(ws + 100 * MiB);  // [100,132) over P-mid (dead after
                                                              //   pass2); live LN1 -> LN2; nothing
                                                              //   writes [100,132) in between (FF1
                                                              //   -> [132,196), FF2 -> [36,68)).
  unsigned short* hbuf  = (unsigned short*)(ws + 132 * MiB);  // [132,196) over P-upper + vt (both
                                                              //   dead after pass2)
  unsigned short* ffb   = (unsigned short*)(ws + 36 * MiB);   // [36,68) over P-lower (dead); NOT
                                                              //   overlapping nattn (round-4 bug)
  float* outp = (float*)d_out;

  k_cast<0><<<dim3(B_ * S1_ / 4), 256, 0, stream>>>(text1, nullptr, qn8);
  k_cast<1><<<dim3(B_ * S2_ / 4), 256, 0, stream>>>(text2, kn, kn8);
  k_tw<<<dim3(512 * 1024 / 256), 256, 0, stream>>>(W1, W1T, 9, 1024);
  k_tw<<<dim3(512 * 1024 / 256), 256, 0, stream>>>(W2, W2T, 10, 512);
  k_tvt<<<dim3(H_ / 64, S2_ / 64, B_), 256, 0, stream>>>(kn, vt);

  // pass1 (fp8 pre-normalized, BK=128), all 16 batches: P = exp(q8@k8^T - 1)*mask [SWZ=0]
  k_gemm<2, 0, 1><<<dim3(S2_ / 128, S1_ / 128, B_), 256, 0, stream>>>(
      qn8, kn8, nullptr, mask2,
      P, S1_, S2_, H_, (long)S1_ * H_, (long)S2_ * H_, (long)S1_ * S2_);
  // pass2 (bf16), all 16 batches: O = P @ V (unnormalized; LN1 washes row scale)
  k_gemm<3, 1, 0><<<dim3(H_ / 128, S1_ / 128, B_), 256, 0, stream>>>(
      P, vt, nullptr, nullptr,
      O, S1_, H_, S2_, (long)S1_ * S2_ * 2, (long)H_ * S2_ * 2, (long)S1_ * H_);

  k_ln1<<<dim3(B_ * S1_ / 4), 256, 0, stream>>>(O, g1, bb1, nattn);
  k_gemm<0, 1, 0><<<dim3(1024 / 128, 32768 / 128, 1), 256, 0, stream>>>(
      nattn, W1T, b1, nullptr, hbuf, 32768, 1024, 512, 0, 0, 0);
  k_gemm<1, 1, 0><<<dim3(512 / 128, 32768 / 128, 1), 256, 0, stream>>>(
      hbuf, W2T, b2, nullptr, ffb, 32768, 512, 1024, 0, 0, 0);
  k_ln2<<<dim3(32768 / 4), 256, 0, stream>>>(ffb, nattn, text1, g2, bb2, outp);
}